// Round 7
// baseline (117.542 us; speedup 1.0000x reference)
//
#include <hip/hip_runtime.h>
#include <hip/hip_bf16.h>

constexpr int BATCH = 256;
constexpr int VOCAB = 128000;
constexpr int K = 256;
constexpr float IGNORED_C = -3000.0f;

// fast path params
constexpr int NCHUNK = 8;
constexpr int CHUNK = VOCAB / NCHUNK;   // 16000
constexpr int CAP = 512;                // candidate cap == sort width == blockDim
constexpr int N4 = CHUNK / 4;           // 4000 float4 per chunk
constexpr int TAIL = N4 - 7 * 512;      // 416: threads with it==7 valid

// fallback path params
constexpr int FB_BINS = 8192;
constexpr int FB_SHIFT = 19;
constexpr int FB_CAND = 2048;

// order-preserving f32 -> u32 map (larger float => larger key)
__device__ __forceinline__ unsigned mono(unsigned u) {
    return (u & 0x80000000u) ? ~u : (u | 0x80000000u);
}
__device__ __forceinline__ float inv_mono(unsigned k) {
    unsigned u = (k & 0x80000000u) ? (k ^ 0x80000000u) : ~k;
    return __uint_as_float(u);
}

__device__ __forceinline__ uint4 mono4(float4 f) {
    return make_uint4(mono(__float_as_uint(f.x)), mono(__float_as_uint(f.y)),
                      mono(__float_as_uint(f.z)), mono(__float_as_uint(f.w)));
}

// ============================================================================
// K1: per (row, chunk) exact top-256 (value desc, idx asc), sorted, u64 keys.
// Selection: sampled threshold + exact count passes over register data.
// Data lives in NAMED variables r0..r7 and all multi-pass code is macro-
// generated straight-line code: rounds 4-6 used a uint4 r[8] array captured
// by-reference in a lambda, which blocked SROA promotion -> 70-90 MB of
// scratch spill traffic per dispatch (WRITE_SIZE counter).
// ============================================================================
__global__ __launch_bounds__(512, 4)
void k1_topk_chunk(const float* __restrict__ logits,
                   unsigned long long* __restrict__ ws_cand)
{
    __shared__ unsigned long long cand[CAP];
    __shared__ unsigned samp[512];
    __shared__ unsigned wred[16];
    __shared__ unsigned ccount;

    const int tid = threadIdx.x;
    const int wave = tid >> 6, lane = tid & 63;
    const int row = blockIdx.x >> 3;            // NCHUNK == 8
    const int chunk = blockIdx.x & 7;
    const int gbase = chunk * CHUNK;
    const float4* rp4 = reinterpret_cast<const float4*>(
        logits + (size_t)row * VOCAB + (size_t)gbase);
    const bool t7 = tid < TAIL;

    // ---- load ~31 floats/thread as monotone keys (one HBM sweep) ----
    uint4 r0 = mono4(rp4[tid]);
    uint4 r1 = mono4(rp4[tid + 512]);
    uint4 r2 = mono4(rp4[tid + 1024]);
    uint4 r3 = mono4(rp4[tid + 1536]);
    uint4 r4 = mono4(rp4[tid + 2048]);
    uint4 r5 = mono4(rp4[tid + 2560]);
    uint4 r6 = mono4(rp4[tid + 3072]);
    uint4 r7 = t7 ? mono4(rp4[tid + 3584]) : make_uint4(0u, 0u, 0u, 0u);

    const unsigned b0 = 4u * (unsigned)tid;

// count one uint4 against threshold T_ (greater / equal-with-index-bound)
#define CNTQ(q, qb) \
    cgt += (q.x > T_); ceq += (q.x == T_ && (qb + 0u) <= X_); \
    cgt += (q.y > T_); ceq += (q.y == T_ && (qb + 1u) <= X_); \
    cgt += (q.z > T_); ceq += (q.z == T_ && (qb + 2u) <= X_); \
    cgt += (q.w > T_); ceq += (q.w == T_ && (qb + 3u) <= X_);

// exact block-wide count: NGT = #(key > T), NEQ = #(key == T && loc <= X)
#define COUNT_PASS(Tv, Xv, NGT, NEQ) do { \
    const unsigned T_ = (Tv), X_ = (Xv); \
    unsigned cgt = 0u, ceq = 0u; \
    CNTQ(r0, (b0))           CNTQ(r1, (b0 + 2048u)) \
    CNTQ(r2, (b0 + 4096u))   CNTQ(r3, (b0 + 6144u)) \
    CNTQ(r4, (b0 + 8192u))   CNTQ(r5, (b0 + 10240u)) \
    CNTQ(r6, (b0 + 12288u)) \
    if (t7) { CNTQ(r7, (b0 + 14336u)) } \
    for (int off_ = 32; off_ >= 1; off_ >>= 1) { \
        cgt += __shfl_xor(cgt, off_); \
        ceq += __shfl_xor(ceq, off_); \
    } \
    __syncthreads(); \
    if (lane == 0) { wred[wave] = cgt; wred[8 + wave] = ceq; } \
    __syncthreads(); \
    unsigned g_ = 0u, e_ = 0u; \
    for (int w2_ = 0; w2_ < 8; ++w2_) { g_ += wred[w2_]; e_ += wred[8 + w2_]; } \
    (NGT) = g_; (NEQ) = e_; \
} while (0)

    // ---- sample: one key per thread (first quarter of chunk), sort desc ----
    {
        const int j2 = tid & 3, c = (tid >> 2) & 3;
        uint4 f = r0;
        if (j2 == 1) f = r1;
        if (j2 == 2) f = r2;
        if (j2 == 3) f = r3;
        unsigned sv = f.x;
        if (c == 1) sv = f.y;
        if (c == 2) sv = f.z;
        if (c == 3) sv = f.w;

        unsigned v = sv;
        #pragma unroll
        for (int kk = 2; kk <= 512; kk <<= 1) {
            for (int j = kk >> 1; j > 0; j >>= 1) {
                const bool keepMax = (((tid & kk) == 0) == ((tid & j) == 0));
                unsigned w;
                if (j >= 64) {
                    __syncthreads();
                    samp[tid] = v;
                    __syncthreads();
                    w = samp[tid ^ j];
                } else {
                    w = __shfl_xor(v, j);
                }
                v = keepMax ? (v >= w ? v : w) : (v <= w ? v : w);
            }
        }
        __syncthreads();
        samp[tid] = v;                   // sorted descending
        __syncthreads();
    }

    // ---- threshold: T = samp[11] (expected count ~375), verify exactly ----
    unsigned T = samp[11];
    unsigned ngt, neq;
    COUNT_PASS(T, 0xFFFFFFFFu, ngt, neq);
    unsigned nge = ngt + neq;

    if (nge < (unsigned)K || nge > (unsigned)CAP) {
        // rank-space binary search: smallest r with n_ge(samp[r]) >= K
        int lo, hi;
        if (nge < (unsigned)K) { lo = 11; hi = 511; }   // samp[511]: count>=512>=K
        else                   { lo = -1; hi = 11;  }   // samp[11] already >= K
        while (hi - lo > 1) {
            const int mid = (lo + hi) >> 1;
            COUNT_PASS(samp[mid], 0xFFFFFFFFu, ngt, neq);
            if (ngt + neq >= (unsigned)K) hi = mid; else lo = mid;
        }
        T = samp[hi];
        COUNT_PASS(T, 0xFFFFFFFFu, ngt, neq);
        nge = ngt + neq;
        if (nge > (unsigned)CAP) {
            // key-space: largest T0 with n_ge(T0) >= K in (samp[hi], khi]
            unsigned klo = T;
            unsigned khi = (hi > 0) ? samp[hi - 1] : 0xFFFFFFFFu;
            COUNT_PASS(khi, 0xFFFFFFFFu, ngt, neq);
            if (ngt + neq >= (unsigned)K) {
                klo = khi;
            } else {
                while (khi - klo > 1) {
                    const unsigned kmid = klo + ((khi - klo) >> 1);
                    COUNT_PASS(kmid, 0xFFFFFFFFu, ngt, neq);
                    if (ngt + neq >= (unsigned)K) klo = kmid; else khi = kmid;
                }
            }
            T = klo;
            COUNT_PASS(T, 0xFFFFFFFFu, ngt, neq);
            nge = ngt + neq;
        }
    }

    // ---- tie path (pathological duplicates): pick K-ngt smallest indices at T ----
    bool tie = false;
    unsigned X = 0xFFFFFFFFu;
    if (nge > (unsigned)CAP) {
        tie = true;
        const unsigned target = (unsigned)K - ngt;     // ngt < K by maximality of T
        int xlo = -1, xhi = CHUNK - 1;
        while (xhi - xlo > 1) {
            const int xmid = (xlo + xhi) >> 1;
            unsigned g2, e2;
            COUNT_PASS(T, (unsigned)xmid, g2, e2);
            if (e2 >= target) xhi = xmid; else xlo = xmid;
        }
        X = (unsigned)xhi;
    }

    // ---- collect candidates from registers ----
    if (tid == 0) ccount = 0u;
    __syncthreads();

#define COLQ1(kx, qb) { \
    const unsigned loc_ = (qb); \
    if ((kx > T) || (kx == T && (!tie || loc_ <= X))) { \
        const unsigned p_ = atomicAdd(&ccount, 1u); \
        if (p_ < (unsigned)CAP) \
            cand[p_] = ((unsigned long long)kx << 32) | (unsigned)(~(gbase + (int)loc_)); \
    } }
#define COLQ(q, qb) COLQ1(q.x, (qb)+0u) COLQ1(q.y, (qb)+1u) COLQ1(q.z, (qb)+2u) COLQ1(q.w, (qb)+3u)

    COLQ(r0, b0)            COLQ(r1, b0 + 2048u)
    COLQ(r2, b0 + 4096u)    COLQ(r3, b0 + 6144u)
    COLQ(r4, b0 + 8192u)    COLQ(r5, b0 + 10240u)
    COLQ(r6, b0 + 12288u)
    if (t7) { COLQ(r7, b0 + 14336u) }

    __syncthreads();
    const unsigned cc = ccount;
    if ((unsigned)tid >= cc) cand[tid] = 0ull;   // pad (always < any candidate)
    __syncthreads();

    // ---- hybrid bitonic sort 512 candidates (u64), descending ----
    unsigned long long v = cand[tid];
    #pragma unroll
    for (int kk = 2; kk <= CAP; kk <<= 1) {
        for (int j = kk >> 1; j > 0; j >>= 1) {
            const bool keepMax = (((tid & kk) == 0) == ((tid & j) == 0));
            unsigned long long w;
            if (j >= 64) {
                __syncthreads();
                cand[tid] = v;
                __syncthreads();
                w = cand[tid ^ j];
            } else {
                w = __shfl_xor(v, j);
            }
            v = keepMax ? (v >= w ? v : w) : (v <= w ? v : w);
        }
    }

    if (tid < K) ws_cand[(size_t)blockIdx.x * K + tid] = v;
}

// ============================================================================
// K2: per row merge 8 sorted runs (bitonic merge stages only) + pipeline
// ============================================================================
__global__ __launch_bounds__(1024)
void k2_merge(const float* __restrict__ params,
              const unsigned long long* __restrict__ ws_cand,
              float* __restrict__ ws_v, float* __restrict__ ws_csum,
              int* __restrict__ ws_idx, float* __restrict__ ws_p0)
{
    constexpr int N = NCHUNK * K;   // 2048
    __shared__ unsigned long long cand[N];
    __shared__ float red[K];
    __shared__ float sc[K];

    const int row = blockIdx.x;
    const int tid = threadIdx.x;

    // load; reverse odd runs so runs alternate desc/asc (valid bitonic state k=256)
    for (int i = tid; i < N; i += 1024) {
        const int c = i >> 8, pos = i & (K - 1);
        unsigned long long v = ws_cand[(size_t)row * N + i];
        const int dest = (c & 1) ? ((c << 8) | (K - 1 - pos)) : i;
        cand[dest] = v;
    }
    __syncthreads();

    // bitonic merge stages k = 512, 1024, 2048 (descending overall)
    for (int kk2 = 2 * K; kk2 <= N; kk2 <<= 1) {
        for (int j = kk2 >> 1; j > 0; j >>= 1) {
            for (int i = tid; i < N; i += 1024) {
                const int ixj = i ^ j;
                if (ixj > i) {
                    unsigned long long a = cand[i], b = cand[ixj];
                    bool sw = ((i & kk2) == 0) ? (a < b) : (a > b);
                    if (sw) { cand[i] = b; cand[ixj] = a; }
                }
            }
            __syncthreads();
        }
    }

    // pipeline on top-256: topk-mask -> /temp -> softmax -> cumsum
    const bool act = tid < K;
    const float topk_f = params[row * 3 + 0];
    const float temp   = params[row * 3 + 2];
    float v = 0.f;
    int myidx = 0;
    if (act) {
        unsigned long long c = cand[tid];
        float val = inv_mono((unsigned)(c >> 32));
        myidx = (int)(~(unsigned)c);
        float x = (((float)tid) >= topk_f) ? IGNORED_C : val;
        v = x / temp;
        red[tid] = v;
    }
    __syncthreads();
    for (int s = K / 2; s > 0; s >>= 1) {
        if (tid < s) red[tid] = fmaxf(red[tid], red[tid + s]);
        __syncthreads();
    }
    const float m = red[0];
    __syncthreads();
    const float e = act ? expf(v - m) : 0.f;
    if (act) red[tid] = e;
    __syncthreads();
    for (int s = K / 2; s > 0; s >>= 1) {
        if (tid < s) red[tid] += red[tid + s];
        __syncthreads();
    }
    const float ssum = red[0];
    __syncthreads();
    const float p = e / ssum;
    if (act) sc[tid] = p;
    __syncthreads();
    for (int off = 1; off < K; off <<= 1) {
        float t = 0.f;
        if (act && tid >= off) t = sc[tid - off];
        __syncthreads();
        if (act) sc[tid] += t;
        __syncthreads();
    }
    if (act) {
        ws_v[row * K + tid]    = v;
        ws_csum[row * K + tid] = sc[tid];
        ws_idx[row * K + tid]  = myidx;
    }
    if (tid == 0) ws_p0[row] = p;   // probs[0] == csum[0]
}

// ============================================================================
// K3: global-min(p0) -> top-p mask -> softmax -> cumsum -> sample
// ============================================================================
__global__ __launch_bounds__(K)
void k3_sample(const float* __restrict__ params,
               const float* __restrict__ rand_u,
               const float* __restrict__ ws_v,
               const float* __restrict__ ws_csum,
               const int* __restrict__ ws_idx,
               const float* __restrict__ ws_p0,
               int* __restrict__ out)
{
    __shared__ float red[K];
    __shared__ float sc[K];
    const int row = blockIdx.x;
    const int tid = threadIdx.x;

    red[tid] = ws_p0[tid];          // BATCH == 256 == blockDim
    __syncthreads();
    for (int s = K / 2; s > 0; s >>= 1) {
        if (tid < s) red[tid] = fminf(red[tid], red[tid + s]);
        __syncthreads();
    }
    const float tpe = fmaxf(red[0], params[row * 3 + 1]);
    __syncthreads();

    const float csum = ws_csum[row * K + tid];
    const float v0   = ws_v[row * K + tid];
    const float v2 = ((csum > tpe) && (tid != 0)) ? IGNORED_C : v0;
    red[tid] = v2;
    __syncthreads();
    for (int s = K / 2; s > 0; s >>= 1) {
        if (tid < s) red[tid] = fmaxf(red[tid], red[tid + s]);
        __syncthreads();
    }
    const float m = red[0];
    __syncthreads();
    const float e = expf(v2 - m);
    red[tid] = e;
    __syncthreads();
    for (int s = K / 2; s > 0; s >>= 1) {
        if (tid < s) red[tid] += red[tid + s];
        __syncthreads();
    }
    const float ssum = red[0];
    __syncthreads();
    const float p = e / ssum;
    sc[tid] = p;
    __syncthreads();
    for (int off = 1; off < K; off <<= 1) {
        float t = (tid >= off) ? sc[tid - off] : 0.f;
        __syncthreads();
        sc[tid] += t;
        __syncthreads();
    }
    const float ru = rand_u[row];
    red[tid] = (ru > sc[tid]) ? 1.f : 0.f;
    __syncthreads();
    for (int s = K / 2; s > 0; s >>= 1) {
        if (tid < s) red[tid] += red[tid + s];
        __syncthreads();
    }
    if (tid == 0) {
        int sel = (int)red[0];
        if (sel > K - 1) sel = K - 1;
        out[row] = ws_idx[row * K + sel];
    }
}

// ============================================================================
// Fallback (round-1 proven): single block per row, used only if ws too small
// ============================================================================
__global__ __launch_bounds__(1024)
void fb_stage1(const float* __restrict__ logits,
               const float* __restrict__ params,
               float* __restrict__ ws_v,
               float* __restrict__ ws_csum,
               int* __restrict__ ws_idx,
               float* __restrict__ ws_p0)
{
    __shared__ unsigned hist[FB_BINS];
    __shared__ unsigned gsum[128];
    __shared__ unsigned long long cand[FB_CAND];
    __shared__ unsigned ccount;
    __shared__ int tbin;
    __shared__ float sv[K];
    __shared__ float se[K];
    __shared__ int   sidx[K];
    __shared__ float sred;

    const int row = blockIdx.x;
    const int tid = threadIdx.x;
    const float4* rp4 = reinterpret_cast<const float4*>(logits + (size_t)row * VOCAB);

    for (int i = tid; i < FB_BINS; i += 1024) hist[i] = 0u;
    __syncthreads();
    for (int i = tid; i < VOCAB / 4; i += 1024) {
        float4 v = rp4[i];
        atomicAdd(&hist[mono(__float_as_uint(v.x)) >> FB_SHIFT], 1u);
        atomicAdd(&hist[mono(__float_as_uint(v.y)) >> FB_SHIFT], 1u);
        atomicAdd(&hist[mono(__float_as_uint(v.z)) >> FB_SHIFT], 1u);
        atomicAdd(&hist[mono(__float_as_uint(v.w)) >> FB_SHIFT], 1u);
    }
    __syncthreads();
    if (tid < 128) {
        unsigned s = 0;
        for (int i = 0; i < 64; ++i) s += hist[tid * 64 + i];
        gsum[tid] = s;
    }
    __syncthreads();
    if (tid == 0) {
        unsigned acc = 0;
        int g = 127;
        for (; g > 0; --g) {
            if (acc + gsum[g] >= (unsigned)K) break;
            acc += gsum[g];
        }
        int t = g * 64;
        for (int bin = g * 64 + 63; bin >= g * 64; --bin) {
            acc += hist[bin];
            if (acc >= (unsigned)K) { t = bin; break; }
        }
        tbin = t;
        ccount = 0u;
    }
    __syncthreads();
    const unsigned tb = (unsigned)tbin;
    for (int i = tid; i < VOCAB / 4; i += 1024) {
        float4 v = rp4[i];
        const int base = i * 4;
        unsigned kk[4] = { mono(__float_as_uint(v.x)), mono(__float_as_uint(v.y)),
                           mono(__float_as_uint(v.z)), mono(__float_as_uint(v.w)) };
        #pragma unroll
        for (int c = 0; c < 4; ++c) {
            if ((kk[c] >> FB_SHIFT) >= tb) {
                unsigned p = atomicAdd(&ccount, 1u);
                if (p < FB_CAND)
                    cand[p] = ((unsigned long long)kk[c] << 32) | (unsigned)(~(base + c));
            }
        }
    }
    __syncthreads();
    for (int i = tid; i < FB_CAND; i += 1024)
        if ((unsigned)i >= ccount) cand[i] = 0ull;
    __syncthreads();
    for (int k = 2; k <= FB_CAND; k <<= 1) {
        for (int j = k >> 1; j > 0; j >>= 1) {
            for (int i = tid; i < FB_CAND; i += 1024) {
                int ixj = i ^ j;
                if (ixj > i) {
                    unsigned long long a = cand[i], b = cand[ixj];
                    bool sw = ((i & k) == 0) ? (a < b) : (a > b);
                    if (sw) { cand[i] = b; cand[ixj] = a; }
                }
            }
            __syncthreads();
        }
    }
    const float topk_f = params[row * 3 + 0];
    const float temp   = params[row * 3 + 2];
    if (tid < K) {
        unsigned long long c = cand[tid];
        float val = inv_mono((unsigned)(c >> 32));
        sidx[tid] = (int)(~(unsigned)c);
        float v = (((float)tid) >= topk_f) ? IGNORED_C : val;
        sv[tid] = v / temp;
    }
    __syncthreads();
    if (tid == 0) {
        float mm = sv[0];
        for (int i = 1; i < K; ++i) mm = fmaxf(mm, sv[i]);
        sred = mm;
    }
    __syncthreads();
    if (tid < K) se[tid] = expf(sv[tid] - sred);
    __syncthreads();
    if (tid == 0) {
        float s = 0.f;
        for (int i = 0; i < K; ++i) s += se[i];
        sred = s;
    }
    __syncthreads();
    if (tid < K) se[tid] = se[tid] / sred;
    __syncthreads();
    if (tid == 0) {
        float c = 0.f;
        for (int i = 0; i < K; ++i) { c += se[i]; se[i] = c; }
    }
    __syncthreads();
    if (tid < K) {
        ws_v[row * K + tid]    = sv[tid];
        ws_csum[row * K + tid] = se[tid];
        ws_idx[row * K + tid]  = sidx[tid];
    }
    if (tid == 0) ws_p0[row] = se[0];
}

extern "C" void kernel_launch(void* const* d_in, const int* in_sizes, int n_in,
                              void* d_out, int out_size, void* d_ws, size_t ws_size,
                              hipStream_t stream) {
    const float* logits = (const float*)d_in[0];
    const float* params = (const float*)d_in[1];
    const float* randu  = (const float*)d_in[2];
    int* out = (int*)d_out;
    char* ws = (char*)d_ws;

    const size_t cand_bytes = (size_t)BATCH * NCHUNK * K * 8;          // 4 MB
    const size_t tail_bytes = (size_t)3 * BATCH * K * 4 + BATCH * 4;   // 769 KB
    if (ws_size >= cand_bytes + tail_bytes) {
        unsigned long long* ws_cand = (unsigned long long*)ws;
        char* p = ws + cand_bytes;
        float* ws_v    = (float*)(p);
        float* ws_csum = (float*)(p + (size_t)BATCH * K * 4);
        int*   ws_idx  = (int*)  (p + (size_t)2 * BATCH * K * 4);
        float* ws_p0   = (float*)(p + (size_t)3 * BATCH * K * 4);
        hipLaunchKernelGGL(k1_topk_chunk, dim3(BATCH * NCHUNK), dim3(512), 0, stream,
                           logits, ws_cand);
        hipLaunchKernelGGL(k2_merge, dim3(BATCH), dim3(1024), 0, stream,
                           params, ws_cand, ws_v, ws_csum, ws_idx, ws_p0);
        hipLaunchKernelGGL(k3_sample, dim3(BATCH), dim3(K), 0, stream,
                           params, randu, ws_v, ws_csum, ws_idx, ws_p0, out);
    } else {
        float* ws_v    = (float*)(ws);
        float* ws_csum = (float*)(ws + (size_t)BATCH * K * 4);
        int*   ws_idx  = (int*)  (ws + (size_t)2 * BATCH * K * 4);
        float* ws_p0   = (float*)(ws + (size_t)3 * BATCH * K * 4);
        hipLaunchKernelGGL(fb_stage1, dim3(BATCH), dim3(1024), 0, stream,
                           logits, params, ws_v, ws_csum, ws_idx, ws_p0);
        hipLaunchKernelGGL(k3_sample, dim3(BATCH), dim3(K), 0, stream,
                           params, randu, ws_v, ws_csum, ws_idx, ws_p0, out);
    }
}

// Round 8
// 91.230 us; speedup vs baseline: 1.2884x; 1.2884x over previous
//
#include <hip/hip_runtime.h>
#include <hip/hip_bf16.h>

constexpr int BATCH = 256;
constexpr int VOCAB = 128000;
constexpr int K = 256;
constexpr float IGNORED_C = -3000.0f;

// fast path params
constexpr int NCHUNK = 4;
constexpr int CHUNK = VOCAB / NCHUNK;   // 32000
constexpr int N4 = CHUNK / 4;           // 8000 float4 per chunk
constexpr int BINS = 8192;              // top 13 bits of monotone key
constexpr int SHIFT = 19;
constexpr int CAP = 512;                // per-chunk candidate cap
constexpr int N2 = NCHUNK * CAP;        // 2048 candidates per row into k2

// fallback path params
constexpr int FB_BINS = 8192;
constexpr int FB_SHIFT = 19;
constexpr int FB_CAND = 2048;

// order-preserving f32 -> u32 map (larger float => larger key)
__device__ __forceinline__ unsigned mono(unsigned u) {
    return (u & 0x80000000u) ? ~u : (u | 0x80000000u);
}
__device__ __forceinline__ float inv_mono(unsigned k) {
    unsigned u = (k & 0x80000000u) ? (k ^ 0x80000000u) : ~k;
    return __uint_as_float(u);
}

// ============================================================================
// K1: per (row, chunk): LDS histogram -> wave-0 suffix scan -> threshold bin
// -> collect UNSORTED candidates (re-read from L2/L3). No per-chunk sort, no
// register-resident data (rounds 4-7 lesson: data-in-VGPR kills occupancy).
// ~5 barriers per block total.
// ============================================================================
__global__ __launch_bounds__(512)
void k1_select(const float* __restrict__ logits,
               unsigned long long* __restrict__ ws_cand)
{
    __shared__ unsigned hist[BINS];
    __shared__ unsigned part[512];
    __shared__ unsigned long long cand[CAP];
    __shared__ unsigned ccount;
    __shared__ int s_tbin;

    const int tid = threadIdx.x;
    const int row = blockIdx.x >> 2;            // NCHUNK == 4
    const int chunk = blockIdx.x & 3;
    const int gbase = chunk * CHUNK;
    const float4* rp4 = reinterpret_cast<const float4*>(
        logits + (size_t)row * VOCAB + (size_t)gbase);

    for (int i = tid; i < BINS; i += 512) hist[i] = 0u;
    if (tid == 0) ccount = 0u;
    __syncthreads();

    // ---- pass 1: histogram of top-13-bit keys (one HBM sweep) ----
    for (int i = tid; i < N4; i += 512) {
        float4 v = rp4[i];
        atomicAdd(&hist[mono(__float_as_uint(v.x)) >> SHIFT], 1u);
        atomicAdd(&hist[mono(__float_as_uint(v.y)) >> SHIFT], 1u);
        atomicAdd(&hist[mono(__float_as_uint(v.z)) >> SHIFT], 1u);
        atomicAdd(&hist[mono(__float_as_uint(v.w)) >> SHIFT], 1u);
    }
    __syncthreads();

    // ---- group sums of 16 bins each (rotated reads: ~2-way banks) ----
    {
        unsigned s = 0;
        #pragma unroll
        for (int j = 0; j < 16; ++j)
            s += hist[tid * 16 + ((j + tid) & 15)];
        part[tid] = s;
    }
    __syncthreads();

    // ---- wave 0 only: suffix scan over 512 group sums, pick threshold bin t =
    //      max{ b : count(bin >= b) >= K }. No block barriers inside. ----
    if (tid < 64) {
        const int l = tid;
        const unsigned g0 = part[l * 8 + 0], g1 = part[l * 8 + 1];
        const unsigned g2 = part[l * 8 + 2], g3 = part[l * 8 + 3];
        const unsigned g4 = part[l * 8 + 4], g5 = part[l * 8 + 5];
        const unsigned g6 = part[l * 8 + 6], g7 = part[l * 8 + 7];
        const unsigned s7 = g7;
        const unsigned s6 = s7 + g6;
        const unsigned s5 = s6 + g5;
        const unsigned s4 = s5 + g4;
        const unsigned s3 = s4 + g3;
        const unsigned s2 = s3 + g2;
        const unsigned s1 = s2 + g1;
        const unsigned s0 = s1 + g0;        // lane total
        unsigned suf = s0;                  // inclusive suffix across lanes
        #pragma unroll
        for (int off = 1; off < 64; off <<= 1) {
            unsigned t = __shfl_down(suf, off);
            if (l + off < 64) suf += t;
        }
        const unsigned hi = suf - s0;       // sum over lanes > l
        const bool finder = (hi < (unsigned)K) && (hi + s0 >= (unsigned)K);
        // largest j in this lane with hi + s_j >= K, and base = suffix above it
        int jj; unsigned base;
        if      (hi + s7 >= (unsigned)K) { jj = 7; base = hi; }
        else if (hi + s6 >= (unsigned)K) { jj = 6; base = hi + s7; }
        else if (hi + s5 >= (unsigned)K) { jj = 5; base = hi + s6; }
        else if (hi + s4 >= (unsigned)K) { jj = 4; base = hi + s5; }
        else if (hi + s3 >= (unsigned)K) { jj = 3; base = hi + s4; }
        else if (hi + s2 >= (unsigned)K) { jj = 2; base = hi + s3; }
        else if (hi + s1 >= (unsigned)K) { jj = 1; base = hi + s2; }
        else                             { jj = 0; base = hi + s1; }
        int tg = l * 8 + jj;
        const unsigned long long fm = __ballot(finder);
        const int src = __ffsll((unsigned long long)fm) - 1;
        tg   = __shfl(tg, src);
        base = __shfl(base, src);
        // fine bin within group tg: 16 lanes, suffix + ballot
        unsigned h = (l < 16) ? hist[tg * 16 + l] : 0u;
        unsigned suf16 = h;
        #pragma unroll
        for (int off = 1; off < 16; off <<= 1) {
            unsigned t = __shfl_down(suf16, off);
            if (l + off < 16) suf16 += t;
        }
        const bool qual = (l < 16) && (base + suf16 >= (unsigned)K);
        const unsigned long long qm = __ballot(qual);
        if (l == 0) s_tbin = tg * 16 + (63 - __builtin_clzll(qm));
    }
    __syncthreads();

    // ---- pass 2: collect candidates with bin >= tbin (re-read from L3) ----
    const unsigned tb = (unsigned)s_tbin;
    for (int i = tid; i < N4; i += 512) {
        float4 v = rp4[i];
        const int base = gbase + i * 4;
        const unsigned ka = mono(__float_as_uint(v.x));
        const unsigned kb = mono(__float_as_uint(v.y));
        const unsigned kc = mono(__float_as_uint(v.z));
        const unsigned kd = mono(__float_as_uint(v.w));
        if ((ka >> SHIFT) >= tb) { unsigned p = atomicAdd(&ccount, 1u); if (p < CAP) cand[p] = ((unsigned long long)ka << 32) | (unsigned)(~(base + 0)); }
        if ((kb >> SHIFT) >= tb) { unsigned p = atomicAdd(&ccount, 1u); if (p < CAP) cand[p] = ((unsigned long long)kb << 32) | (unsigned)(~(base + 1)); }
        if ((kc >> SHIFT) >= tb) { unsigned p = atomicAdd(&ccount, 1u); if (p < CAP) cand[p] = ((unsigned long long)kc << 32) | (unsigned)(~(base + 2)); }
        if ((kd >> SHIFT) >= tb) { unsigned p = atomicAdd(&ccount, 1u); if (p < CAP) cand[p] = ((unsigned long long)kd << 32) | (unsigned)(~(base + 3)); }
    }
    __syncthreads();

    // ---- write unsorted candidates, zero-padded to CAP ----
    const unsigned cc = ccount;
    ws_cand[(size_t)blockIdx.x * CAP + tid] = ((unsigned)tid < cc) ? cand[tid] : 0ull;
}

// ============================================================================
// K2: per row: load 4x512 candidates -> bitonic sort 2048 desc (exact order:
// value desc, idx asc via u64 key) -> top-256 pipeline (mask/temp/softmax/
// cumsum) -> ws. Only 256 blocks pay the sort cost.
// ============================================================================
__global__ __launch_bounds__(512)
void k2_sortsel(const float* __restrict__ params,
                const unsigned long long* __restrict__ ws_cand,
                float* __restrict__ ws_v, float* __restrict__ ws_csum,
                int* __restrict__ ws_idx, float* __restrict__ ws_p0)
{
    __shared__ unsigned long long buf[N2];
    __shared__ float red[K];
    __shared__ float sc[K];

    const int row = blockIdx.x;
    const int tid = threadIdx.x;

    for (int i = tid; i < N2; i += 512)
        buf[i] = ws_cand[(size_t)row * N2 + i];
    __syncthreads();

    // full bitonic sort, descending
    for (int k = 2; k <= N2; k <<= 1) {
        for (int j = k >> 1; j > 0; j >>= 1) {
            for (int i = tid; i < N2; i += 512) {
                const int ixj = i ^ j;
                if (ixj > i) {
                    const unsigned long long a = buf[i], b = buf[ixj];
                    const bool sw = ((i & k) == 0) ? (a < b) : (a > b);
                    if (sw) { buf[i] = b; buf[ixj] = a; }
                }
            }
            __syncthreads();
        }
    }

    // pipeline on top-256: topk-mask -> /temp -> softmax -> cumsum
    const bool act = tid < K;
    const float topk_f = params[row * 3 + 0];
    const float temp   = params[row * 3 + 2];
    float v = 0.f;
    int myidx = 0;
    if (act) {
        const unsigned long long c = buf[tid];
        const float val = inv_mono((unsigned)(c >> 32));
        myidx = (int)(~(unsigned)c);
        const float x = (((float)tid) >= topk_f) ? IGNORED_C : val;
        v = x / temp;
        red[tid] = v;
    }
    __syncthreads();
    for (int s = K / 2; s > 0; s >>= 1) {
        if (tid < s) red[tid] = fmaxf(red[tid], red[tid + s]);
        __syncthreads();
    }
    const float m = red[0];
    __syncthreads();
    const float e = act ? expf(v - m) : 0.f;
    if (act) red[tid] = e;
    __syncthreads();
    for (int s = K / 2; s > 0; s >>= 1) {
        if (tid < s) red[tid] += red[tid + s];
        __syncthreads();
    }
    const float ssum = red[0];
    __syncthreads();
    const float p = e / ssum;
    if (act) sc[tid] = p;
    __syncthreads();
    for (int off = 1; off < K; off <<= 1) {
        float t = 0.f;
        if (act && tid >= off) t = sc[tid - off];
        __syncthreads();
        if (act) sc[tid] += t;
        __syncthreads();
    }
    if (act) {
        ws_v[row * K + tid]    = v;
        ws_csum[row * K + tid] = sc[tid];
        ws_idx[row * K + tid]  = myidx;
    }
    if (tid == 0) ws_p0[row] = p;   // probs[0] == csum[0]
}

// ============================================================================
// K3: global-min(p0) -> top-p mask -> softmax -> cumsum -> sample
// ============================================================================
__global__ __launch_bounds__(K)
void k3_sample(const float* __restrict__ params,
               const float* __restrict__ rand_u,
               const float* __restrict__ ws_v,
               const float* __restrict__ ws_csum,
               const int* __restrict__ ws_idx,
               const float* __restrict__ ws_p0,
               int* __restrict__ out)
{
    __shared__ float red[K];
    __shared__ float sc[K];
    const int row = blockIdx.x;
    const int tid = threadIdx.x;

    red[tid] = ws_p0[tid];          // BATCH == 256 == blockDim
    __syncthreads();
    for (int s = K / 2; s > 0; s >>= 1) {
        if (tid < s) red[tid] = fminf(red[tid], red[tid + s]);
        __syncthreads();
    }
    const float tpe = fmaxf(red[0], params[row * 3 + 1]);
    __syncthreads();

    const float csum = ws_csum[row * K + tid];
    const float v0   = ws_v[row * K + tid];
    const float v2 = ((csum > tpe) && (tid != 0)) ? IGNORED_C : v0;
    red[tid] = v2;
    __syncthreads();
    for (int s = K / 2; s > 0; s >>= 1) {
        if (tid < s) red[tid] = fmaxf(red[tid], red[tid + s]);
        __syncthreads();
    }
    const float m = red[0];
    __syncthreads();
    const float e = expf(v2 - m);
    red[tid] = e;
    __syncthreads();
    for (int s = K / 2; s > 0; s >>= 1) {
        if (tid < s) red[tid] += red[tid + s];
        __syncthreads();
    }
    const float ssum = red[0];
    __syncthreads();
    const float p = e / ssum;
    sc[tid] = p;
    __syncthreads();
    for (int off = 1; off < K; off <<= 1) {
        float t = (tid >= off) ? sc[tid - off] : 0.f;
        __syncthreads();
        sc[tid] += t;
        __syncthreads();
    }
    const float ru = rand_u[row];
    red[tid] = (ru > sc[tid]) ? 1.f : 0.f;
    __syncthreads();
    for (int s = K / 2; s > 0; s >>= 1) {
        if (tid < s) red[tid] += red[tid + s];
        __syncthreads();
    }
    if (tid == 0) {
        int sel = (int)red[0];
        if (sel > K - 1) sel = K - 1;
        out[row] = ws_idx[row * K + sel];
    }
}

// ============================================================================
// Fallback (round-1 proven): single block per row, used only if ws too small
// ============================================================================
__global__ __launch_bounds__(1024)
void fb_stage1(const float* __restrict__ logits,
               const float* __restrict__ params,
               float* __restrict__ ws_v,
               float* __restrict__ ws_csum,
               int* __restrict__ ws_idx,
               float* __restrict__ ws_p0)
{
    __shared__ unsigned hist[FB_BINS];
    __shared__ unsigned gsum[128];
    __shared__ unsigned long long cand[FB_CAND];
    __shared__ unsigned ccount;
    __shared__ int tbin;
    __shared__ float sv[K];
    __shared__ float se[K];
    __shared__ int   sidx[K];
    __shared__ float sred;

    const int row = blockIdx.x;
    const int tid = threadIdx.x;
    const float4* rp4 = reinterpret_cast<const float4*>(logits + (size_t)row * VOCAB);

    for (int i = tid; i < FB_BINS; i += 1024) hist[i] = 0u;
    __syncthreads();
    for (int i = tid; i < VOCAB / 4; i += 1024) {
        float4 v = rp4[i];
        atomicAdd(&hist[mono(__float_as_uint(v.x)) >> FB_SHIFT], 1u);
        atomicAdd(&hist[mono(__float_as_uint(v.y)) >> FB_SHIFT], 1u);
        atomicAdd(&hist[mono(__float_as_uint(v.z)) >> FB_SHIFT], 1u);
        atomicAdd(&hist[mono(__float_as_uint(v.w)) >> FB_SHIFT], 1u);
    }
    __syncthreads();
    if (tid < 128) {
        unsigned s = 0;
        for (int i = 0; i < 64; ++i) s += hist[tid * 64 + i];
        gsum[tid] = s;
    }
    __syncthreads();
    if (tid == 0) {
        unsigned acc = 0;
        int g = 127;
        for (; g > 0; --g) {
            if (acc + gsum[g] >= (unsigned)K) break;
            acc += gsum[g];
        }
        int t = g * 64;
        for (int bin = g * 64 + 63; bin >= g * 64; --bin) {
            acc += hist[bin];
            if (acc >= (unsigned)K) { t = bin; break; }
        }
        tbin = t;
        ccount = 0u;
    }
    __syncthreads();
    const unsigned tb = (unsigned)tbin;
    for (int i = tid; i < VOCAB / 4; i += 1024) {
        float4 v = rp4[i];
        const int base = i * 4;
        unsigned kk[4] = { mono(__float_as_uint(v.x)), mono(__float_as_uint(v.y)),
                           mono(__float_as_uint(v.z)), mono(__float_as_uint(v.w)) };
        #pragma unroll
        for (int c = 0; c < 4; ++c) {
            if ((kk[c] >> FB_SHIFT) >= tb) {
                unsigned p = atomicAdd(&ccount, 1u);
                if (p < FB_CAND)
                    cand[p] = ((unsigned long long)kk[c] << 32) | (unsigned)(~(base + c));
            }
        }
    }
    __syncthreads();
    for (int i = tid; i < FB_CAND; i += 1024)
        if ((unsigned)i >= ccount) cand[i] = 0ull;
    __syncthreads();
    for (int k = 2; k <= FB_CAND; k <<= 1) {
        for (int j = k >> 1; j > 0; j >>= 1) {
            for (int i = tid; i < FB_CAND; i += 1024) {
                int ixj = i ^ j;
                if (ixj > i) {
                    unsigned long long a = cand[i], b = cand[ixj];
                    bool sw = ((i & k) == 0) ? (a < b) : (a > b);
                    if (sw) { cand[i] = b; cand[ixj] = a; }
                }
            }
            __syncthreads();
        }
    }
    const float topk_f = params[row * 3 + 0];
    const float temp   = params[row * 3 + 2];
    if (tid < K) {
        unsigned long long c = cand[tid];
        float val = inv_mono((unsigned)(c >> 32));
        sidx[tid] = (int)(~(unsigned)c);
        float v = (((float)tid) >= topk_f) ? IGNORED_C : val;
        sv[tid] = v / temp;
    }
    __syncthreads();
    if (tid == 0) {
        float mm = sv[0];
        for (int i = 1; i < K; ++i) mm = fmaxf(mm, sv[i]);
        sred = mm;
    }
    __syncthreads();
    if (tid < K) se[tid] = expf(sv[tid] - sred);
    __syncthreads();
    if (tid == 0) {
        float s = 0.f;
        for (int i = 0; i < K; ++i) s += se[i];
        sred = s;
    }
    __syncthreads();
    if (tid < K) se[tid] = se[tid] / sred;
    __syncthreads();
    if (tid == 0) {
        float c = 0.f;
        for (int i = 0; i < K; ++i) { c += se[i]; se[i] = c; }
    }
    __syncthreads();
    if (tid < K) {
        ws_v[row * K + tid]    = sv[tid];
        ws_csum[row * K + tid] = se[tid];
        ws_idx[row * K + tid]  = sidx[tid];
    }
    if (tid == 0) ws_p0[row] = se[0];
}

extern "C" void kernel_launch(void* const* d_in, const int* in_sizes, int n_in,
                              void* d_out, int out_size, void* d_ws, size_t ws_size,
                              hipStream_t stream) {
    const float* logits = (const float*)d_in[0];
    const float* params = (const float*)d_in[1];
    const float* randu  = (const float*)d_in[2];
    int* out = (int*)d_out;
    char* ws = (char*)d_ws;

    const size_t cand_bytes = (size_t)BATCH * NCHUNK * CAP * 8;        // 4 MB
    const size_t tail_bytes = (size_t)3 * BATCH * K * 4 + BATCH * 4;   // 769 KB
    if (ws_size >= cand_bytes + tail_bytes) {
        unsigned long long* ws_cand = (unsigned long long*)ws;
        char* p = ws + cand_bytes;
        float* ws_v    = (float*)(p);
        float* ws_csum = (float*)(p + (size_t)BATCH * K * 4);
        int*   ws_idx  = (int*)  (p + (size_t)2 * BATCH * K * 4);
        float* ws_p0   = (float*)(p + (size_t)3 * BATCH * K * 4);
        hipLaunchKernelGGL(k1_select, dim3(BATCH * NCHUNK), dim3(512), 0, stream,
                           logits, ws_cand);
        hipLaunchKernelGGL(k2_sortsel, dim3(BATCH), dim3(512), 0, stream,
                           params, ws_cand, ws_v, ws_csum, ws_idx, ws_p0);
        hipLaunchKernelGGL(k3_sample, dim3(BATCH), dim3(K), 0, stream,
                           params, randu, ws_v, ws_csum, ws_idx, ws_p0, out);
    } else {
        float* ws_v    = (float*)(ws);
        float* ws_csum = (float*)(ws + (size_t)BATCH * K * 4);
        int*   ws_idx  = (int*)  (ws + (size_t)2 * BATCH * K * 4);
        float* ws_p0   = (float*)(ws + (size_t)3 * BATCH * K * 4);
        hipLaunchKernelGGL(fb_stage1, dim3(BATCH), dim3(1024), 0, stream,
                           logits, params, ws_v, ws_csum, ws_idx, ws_p0);
        hipLaunchKernelGGL(k3_sample, dim3(BATCH), dim3(K), 0, stream,
                           params, randu, ws_v, ws_csum, ws_idx, ws_p0, out);
    }
}